// Round 16
// baseline (70.244 us; speedup 1.0000x reference)
//
#include <hip/hip_runtime.h>
#include <cfloat>
#include <climits>

#define B_   8
#define N1_  1024
#define N2_  4096
#define C_   256
#define TPQ  16                 // lanes per query
#define QPB  (256 / TPQ)        // 16 queries per block

typedef float vf2 __attribute__((ext_vector_type(2)));

__device__ __forceinline__ unsigned umin_(unsigned a, unsigned b) { return a < b ? a : b; }

// Guaranteed single-op median-of-3 (u32).
__device__ __forceinline__ unsigned umed3_(unsigned a, unsigned b, unsigned c) {
    unsigned d;
    asm("v_med3_u32 %0, %1, %2, %3" : "=v"(d) : "v"(a), "v"(b), "v"(c));
    return d;
}

// Sorted-quad insert (invariant k0<=k1<=k2<=k3): min + 3x med3 = 4 VALU ops.
#define KINS4(k, k0, k1, k2, k3) do {                 \
    unsigned _n1 = umed3_((k), k0, k1);               \
    unsigned _n2 = umed3_((k), k1, k2);               \
    unsigned _n3 = umed3_((k), k2, k3);               \
    k0 = umin_((k), k0);  k1 = _n1;  k2 = _n2;  k3 = _n3; \
} while (0)

// ---------------------------------------------------------------------------
// Kernel 0 (prep): per batch, sort candidates by rho=|p1| (u64 bitonic in
// LDS, key = rho_bits<<32 | idx), emit sorted-order tables:
//   SQ[k] = {2x[s2k],2x[s2k+1],2y[s2k],2y[s2k+1]}   (pair-interleaved, slots)
//   SR[k] = {2z[s2k],2z[s2k+1],s1[s2k],s1[s2k+1]}
//   RHO[slot], OIDX[slot]
// Pre-doubling / s1 use the exact reference-order ops (same values as R15).
// ---------------------------------------------------------------------------
__global__ __launch_bounds__(256) void prep_kernel(
    const float* __restrict__ p1, float4* __restrict__ SQ,
    float4* __restrict__ SR, float* __restrict__ RHO, int* __restrict__ OIDX) {
    __shared__ unsigned long long key[N1_];          // 8 KB
    __shared__ float sx[N1_], sy[N1_], sz[N1_], ss[N1_];  // 16 KB

    const int b   = blockIdx.x;
    const int tid = threadIdx.x;

    for (int i = tid; i < N1_; i += 256) {
        float x = p1[((size_t)b * N1_ + i) * 3 + 0];
        float y = p1[((size_t)b * N1_ + i) * 3 + 1];
        float z = p1[((size_t)b * N1_ + i) * 3 + 2];
        float s1 = __fadd_rn(__fadd_rn(__fmul_rn(x, x), __fmul_rn(y, y)),
                             __fmul_rn(z, z));
        float rho = sqrtf(s1);
        key[i] = ((unsigned long long)__float_as_uint(rho) << 32) | (unsigned)i;
        sx[i] = x; sy[i] = y; sz[i] = z; ss[i] = s1;
    }
    __syncthreads();

    // Bitonic sort ascending (rho >= 0 so uint order == float order).
    for (int k = 2; k <= N1_; k <<= 1) {
        for (int j = k >> 1; j > 0; j >>= 1) {
            for (int i = tid; i < N1_; i += 256) {
                int partner = i ^ j;
                if (partner > i) {
                    bool asc = (i & k) == 0;
                    unsigned long long a = key[i], c = key[partner];
                    if ((a > c) == asc) { key[i] = c; key[partner] = a; }
                }
            }
            __syncthreads();
        }
    }

    for (int s = tid; s < N1_; s += 256) {
        unsigned long long kk = key[s];
        RHO[b * N1_ + s]  = __uint_as_float((unsigned)(kk >> 32));
        OIDX[b * N1_ + s] = (int)(kk & 1023u);
    }
    for (int k2 = tid; k2 < N1_ / 2; k2 += 256) {
        int na = (int)(key[2 * k2] & 1023u);
        int nb = (int)(key[2 * k2 + 1] & 1023u);
        float xa = sx[na], ya = sy[na], za = sz[na], sa = ss[na];
        float xb = sx[nb], yb = sy[nb], zb = sz[nb], sb = ss[nb];
        SQ[b * (N1_ / 2) + k2] = make_float4(xa + xa, xb + xb, ya + ya, yb + yb);
        SR[b * (N1_ / 2) + k2] = make_float4(za + za, zb + zb, sa, sb);
    }
}

// ---------------------------------------------------------------------------
// Kernel 1 (v11): 3-NN with norm-band pruning. Trunc-key top-4 + exact
// rescue (validated R9/R14/R15); candidates scanned in rho-sorted order,
// two-sided 32-slot chunks from |q|'s position; side stops when
// trunc((rho_frontier-|q|)^2) > group-min 4th key + 2 quanta (conservative,
// monotone => all remaining slots on that side provably can't enter top-4).
// ---------------------------------------------------------------------------
__global__ __launch_bounds__(256) void knn_kernel(
    const float4* __restrict__ SQ, const float4* __restrict__ SR,
    const float* __restrict__ RHO, const int* __restrict__ OIDX,
    const float* __restrict__ p2, int4* __restrict__ wsi,
    float4* __restrict__ wsw) {
#pragma clang fp contract(off)
    __shared__ float4 Q[N1_ / 2];   // 8 KB
    __shared__ float4 R[N1_ / 2];   // 8 KB
    __shared__ float  RH[N1_];      // 4 KB
    __shared__ int    OI[N1_];      // 4 KB

    const int tid   = threadIdx.x;
    const int b     = blockIdx.x >> 8;
    const int mtile = blockIdx.x & 255;

#pragma unroll
    for (int i = 0; i < 2; ++i) {
        Q[tid + 256 * i] = SQ[b * (N1_ / 2) + tid + 256 * i];
        R[tid + 256 * i] = SR[b * (N1_ / 2) + tid + 256 * i];
    }
#pragma unroll
    for (int i = 0; i < 4; ++i) {
        RH[tid + 256 * i] = RHO[b * N1_ + tid + 256 * i];
        OI[tid + 256 * i] = OIDX[b * N1_ + tid + 256 * i];
    }
    __syncthreads();

    const int q = tid >> 4;
    const int t = tid & 15;
    const int m = mtile * QPB + q;

    const size_t pbase = ((size_t)b * N2_ + m) * 3;
    const float x2 = p2[pbase + 0];
    const float y2 = p2[pbase + 1];
    const float z2 = p2[pbase + 2];
    const float s2 = __fadd_rn(__fadd_rn(__fmul_rn(x2, x2), __fmul_rn(y2, y2)),
                               __fmul_rn(z2, z2));
    const float qn = sqrtf(s2);

    const vf2 x2v = {x2, x2};
    const vf2 y2v = {y2, y2};
    const vf2 z2v = {z2, z2};
    const vf2 s2v = {s2, s2};

    // Binary search for first slot with RH >= qn (group-uniform).
    int blo = 0, bhi = N1_;
#pragma unroll
    for (int it = 0; it < 10; ++it) {
        int mid = (blo + bhi) >> 1;
        if (RH[mid] < qn) blo = mid + 1; else bhi = mid;
    }
    const int sAligned = blo & ~31;
    int loBase = sAligned - 32;
    int hiBase = sAligned;
    bool doneLo = false, doneHi = false;

    unsigned k0 = UINT_MAX, k1 = UINT_MAX, k2 = UINT_MAX, k3 = UINT_MAX;

#define EVAL_PAIR(baseSlot, CHECK_NEG) do {                                   \
    const int pi_ = ((baseSlot) >> 1) + t;                                    \
    const int pc_ = pi_ < 0 ? 0 : pi_;                                        \
    float4 qv = Q[pc_]; float4 rv = R[pc_];                                   \
    vf2 qx = {qv.x, qv.y}, qy = {qv.z, qv.w};                                 \
    vf2 rz = {rv.x, rv.y}, rs = {rv.z, rv.w};                                 \
    vf2 t1 = qx * x2v, t2 = qy * y2v, t3 = rz * z2v;                          \
    vf2 dot2 = (t1 + t2) + t3;                                                \
    vf2 dd = (s2v - dot2) + rs;                                               \
    const int s0_ = (baseSlot) + 2 * t;                                       \
    unsigned ka = (__float_as_uint(fmaxf(dd.x, 0.f)) & 0xFFFFFC00u)           \
                  | ((unsigned)s0_ & 1023u);                                  \
    unsigned kb = (__float_as_uint(fmaxf(dd.y, 0.f)) & 0xFFFFFC00u)           \
                  | (((unsigned)s0_ + 1u) & 1023u);                           \
    if (CHECK_NEG && s0_ < 0) { ka = 0xFFFFFFFFu; kb = 0xFFFFFFFFu; }         \
    KINS4(ka, k0, k1, k2, k3);                                                \
    KINS4(kb, k0, k1, k2, k3);                                                \
} while (0)

    for (int it = 0; it < 34; ++it) {
        // Group-min 4th key (16-lane butterfly min).
        unsigned k3m = k3;
        k3m = umin_(k3m, (unsigned)__shfl_xor((int)k3m, 1, TPQ));
        k3m = umin_(k3m, (unsigned)__shfl_xor((int)k3m, 2, TPQ));
        k3m = umin_(k3m, (unsigned)__shfl_xor((int)k3m, 4, TPQ));
        k3m = umin_(k3m, (unsigned)__shfl_xor((int)k3m, 8, TPQ));
        const unsigned long long kcmp =
            (unsigned long long)(k3m & 0xFFFFFC00u) + 2048ull;

        doneLo = doneLo || (loBase + 32 <= 0);
        if (!doneLo) {
            const float rf = RH[loBase + 31];
            if (rf < qn) {
                const float df = qn - rf;
                const float bnd = df * df;
                doneLo = ((unsigned long long)(__float_as_uint(bnd)
                          & 0xFFFFFC00u) > kcmp);
            }
        }
        if (!doneLo) { EVAL_PAIR(loBase, true); loBase -= 32; }

        doneHi = doneHi || (hiBase >= N1_);
        if (!doneHi) {
            const float rf = RH[hiBase];
            if (rf > qn) {
                const float df = rf - qn;
                const float bnd = df * df;
                doneHi = ((unsigned long long)(__float_as_uint(bnd)
                          & 0xFFFFFC00u) > kcmp);
            }
        }
        if (!doneHi) { EVAL_PAIR(hiBase, false); hiBase += 32; }

        if (__all(doneLo && doneHi)) break;
    }
#undef EVAL_PAIR

    // Butterfly-merge the 16 lanes' top-4 keys (u32 order, exact).
    for (int mask = 1; mask < TPQ; mask <<= 1) {
        unsigned p0 = (unsigned)__shfl_xor((int)k0, mask, TPQ);
        unsigned p1_ = (unsigned)__shfl_xor((int)k1, mask, TPQ);
        unsigned p2_ = (unsigned)__shfl_xor((int)k2, mask, TPQ);
        unsigned p3_ = (unsigned)__shfl_xor((int)k3, mask, TPQ);
        KINS4(p0,  k0, k1, k2, k3);
        KINS4(p1_, k0, k1, k2, k3);
        KINS4(p2_, k0, k1, k2, k3);
        KINS4(p3_, k0, k1, k2, k3);
    }

    if (t == 0) {
        int   ix[4];
        float dx[4];
#pragma unroll
        for (int k = 0; k < 4; ++k) {
            const unsigned a = k == 0 ? k0 : k == 1 ? k1 : k == 2 ? k2 : k3;
            const int slot = (int)(a & 1023u);
            const int kk = slot >> 1;
            const int h  = slot & 1;
            const float cx = h ? Q[kk].y : Q[kk].x;   // 2x
            const float cy = h ? Q[kk].w : Q[kk].z;   // 2y
            const float cz = h ? R[kk].y : R[kk].x;   // 2z
            const float cs = h ? R[kk].w : R[kk].z;   // s1
            dx[k] = __fadd_rn(__fsub_rn(s2,
                __fadd_rn(__fadd_rn(__fmul_rn(x2, cx), __fmul_rn(y2, cy)),
                          __fmul_rn(z2, cz))), cs);
            ix[k] = OI[slot];
        }
        // Exact lexicographic (d, orig idx) sort-4.
#define CSWAP(a, b) do {                                            \
        bool sw = (dx[b] < dx[a]) || (dx[b] == dx[a] && ix[b] < ix[a]); \
        float td = sw ? dx[b] : dx[a]; dx[b] = sw ? dx[a] : dx[b]; dx[a] = td; \
        int   ti = sw ? ix[b] : ix[a]; ix[b] = sw ? ix[a] : ix[b]; ix[a] = ti; \
    } while (0)
        CSWAP(0, 1); CSWAP(2, 3); CSWAP(0, 2); CSWAP(1, 3); CSWAP(1, 2);
#undef CSWAP

        const float r0 = 1.0f / __fadd_rn(dx[0], 1e-8f);
        const float r1 = 1.0f / __fadd_rn(dx[1], 1e-8f);
        const float r2 = 1.0f / __fadd_rn(dx[2], 1e-8f);
        const float s  = __fadd_rn(__fadd_rn(r0, r1), r2);
        const size_t o = (size_t)b * N2_ + m;
        wsi[o] = make_int4(ix[0], ix[1], ix[2], 0);
        wsw[o] = make_float4(r0 / s, r1 / s, r2 / s, 0.0f);
    }
}

// ---------------------------------------------------------------------------
// Kernel 2 (v4): gather + blend — byte-exact round-6 version (control).
// ---------------------------------------------------------------------------

__global__ __launch_bounds__(256) void blend_kernel(
    const float* __restrict__ x1, const int4* __restrict__ wsi,
    const float4* __restrict__ wsw, float* __restrict__ out) {
    __shared__ float4 L4[N1_];   // 16 KB, XOR-swizzled channel-interleaved

    int bid = blockIdx.x;
    const int mhalf = bid & 1;
    const int ct    = (bid >> 1) & 63;   // 64 channel tiles of 4
    const int b     = bid >> 7;
    const int tid   = threadIdx.x;

    const size_t wbase = (size_t)b * N2_ + (size_t)mhalf * 2048;
    int4   id[8];
    float4 w[8];
#pragma unroll
    for (int mb = 0; mb < 8; ++mb) {
        id[mb] = wsi[wbase + mb * 256 + tid];
        w[mb]  = wsw[wbase + mb * 256 + tid];
    }

    const float* src = x1 + ((size_t)b * C_ + (size_t)ct * 4) * N1_;
    float4 v[4];
#pragma unroll
    for (int c = 0; c < 4; ++c)
        v[c] = reinterpret_cast<const float4*>(src + (size_t)c * N1_)[tid];
#pragma unroll
    for (int e = 0; e < 4; ++e) {
        const int n = 4 * tid + e;
        L4[n ^ ((n >> 3) & 7)] = make_float4((&v[0].x)[e], (&v[1].x)[e],
                                             (&v[2].x)[e], (&v[3].x)[e]);
    }
    __syncthreads();

    const size_t obase = ((size_t)b * C_ + (size_t)ct * 4) * N2_;
#pragma unroll
    for (int mb = 0; mb < 8; ++mb) {
        const int m = mhalf * 2048 + mb * 256 + tid;
        const int na = id[mb].x, nb = id[mb].y, nc = id[mb].z;
        const float4 A  = L4[na ^ ((na >> 3) & 7)];
        const float4 Bv = L4[nb ^ ((nb >> 3) & 7)];
        const float4 Cv = L4[nc ^ ((nc >> 3) & 7)];
        const float wx = w[mb].x, wy = w[mb].y, wz = w[mb].z;
#pragma unroll
        for (int r = 0; r < 4; ++r) {
            float acc = __fadd_rn(__fadd_rn(__fmul_rn((&A.x)[r],  wx),
                                            __fmul_rn((&Bv.x)[r], wy)),
                                  __fmul_rn((&Cv.x)[r], wz));
            __builtin_nontemporal_store(acc, &out[obase + (size_t)r * N2_ + m]);
        }
    }
}

extern "C" void kernel_launch(void* const* d_in, const int* in_sizes, int n_in,
                              void* d_out, int out_size, void* d_ws, size_t ws_size,
                              hipStream_t stream) {
    const float* p1 = (const float*)d_in[0];   // [B, N1, 3]
    const float* x1 = (const float*)d_in[1];   // [B, C, N1]
    const float* p2 = (const float*)d_in[2];   // [B, N2, 3]
    float* out = (float*)d_out;                // [B, C, N2]

    char* ws = (char*)d_ws;
    int4*   wsi  = (int4*)ws;                               // 512 KB
    float4* wsw  = (float4*)(ws + (size_t)B_ * N2_ * 16);   // 512 KB
    float4* SQ   = (float4*)(ws + (size_t)B_ * N2_ * 32);             // 64 KB
    float4* SR   = (float4*)(ws + (size_t)B_ * N2_ * 32 + 65536);     // 64 KB
    float*  RHO  = (float*) (ws + (size_t)B_ * N2_ * 32 + 131072);    // 32 KB
    int*    OIDX = (int*)   (ws + (size_t)B_ * N2_ * 32 + 163840);    // 32 KB

    prep_kernel<<<B_, 256, 0, stream>>>(p1, SQ, SR, RHO, OIDX);
    knn_kernel<<<B_ * (N2_ / QPB), 256, 0, stream>>>(SQ, SR, RHO, OIDX,
                                                     p2, wsi, wsw);
    blend_kernel<<<B_ * (C_ / 4) * 2, 256, 0, stream>>>(x1, wsi, wsw, out);
}

// Round 17
// 28.108 us; speedup vs baseline: 2.4991x; 2.4991x over previous
//
#include <hip/hip_runtime.h>
#include <cfloat>
#include <climits>

#define B_   8
#define N1_  1024
#define N2_  4096
#define C_   256
#define TPQ  16                 // lanes per query
#define QPB  (256 / TPQ)        // 16 queries per block

typedef float vf2 __attribute__((ext_vector_type(2)));

__device__ __forceinline__ unsigned umin_(unsigned a, unsigned b) { return a < b ? a : b; }

// Guaranteed single-op median-of-3 (u32). VOP3, all-VGPR operands.
__device__ __forceinline__ unsigned umed3_(unsigned a, unsigned b, unsigned c) {
    unsigned d;
    asm("v_med3_u32 %0, %1, %2, %3" : "=v"(d) : "v"(a), "v"(b), "v"(c));
    return d;
}

// Sorted-quad insert (invariant k0<=k1<=k2<=k3): min + 3x med3 = 4 VALU ops.
#define KINS4(k, k0, k1, k2, k3) do {                 \
    unsigned _n1 = umed3_((k), k0, k1);               \
    unsigned _n2 = umed3_((k), k1, k2);               \
    unsigned _n3 = umed3_((k), k2, k3);               \
    k0 = umin_((k), k0);  k1 = _n1;  k2 = _n2;  k3 = _n3; \
} while (0)

// ---------------------------------------------------------------------------
// Kernel 1 (v12): 3-NN. R15 structure (pair-interleaved packed-fp32 LDS,
// trunc-key top-4 scan, 16-lane butterfly merge, EXACT rescue) with the
// scan distance folded into packed FMAs:
//   dd_scan = fma(-rz,z2, fma(-qy,y2, fma(-qx,x2, s2))) + s1   [4 pk ops/pair]
// Scan-metric jitter vs reference order is ~2^-23 rel — two decades below
// the trunc quantum (2^-13), absorbed by the validated top-4 margin. The
// rescue recomputes the kept 4 distances in EXACT reference bit order, so
// output bits depend only on the selected set (R9/R14/R15-validated).
// per eval: 2 dist + 2 key + 4 KINS = 8 source ops (was 9.5).
// ---------------------------------------------------------------------------
__global__ __launch_bounds__(256) void knn_kernel(
    const float* __restrict__ p1, const float* __restrict__ p2,
    int4* __restrict__ wsi, float4* __restrict__ wsw) {
#pragma clang fp contract(off)
    __shared__ float4 Q[N1_ / 2];   // 8 KB
    __shared__ float4 R[N1_ / 2];   // 8 KB

    const int tid   = threadIdx.x;
    const int b     = blockIdx.x >> 8;     // 256 query-tiles per batch
    const int mtile = blockIdx.x & 255;

    // Stage coarse points, pair-interleaved, exact pre-doubling (R3 layout).
    for (int k = tid; k < N1_ / 2; k += 256) {
        const float* pa = &p1[((size_t)b * N1_ + 2 * k) * 3];
        float xa = pa[0], ya = pa[1], za = pa[2];
        float xb = pa[3], yb = pa[4], zb = pa[5];
        float sa = __fadd_rn(__fadd_rn(__fmul_rn(xa, xa), __fmul_rn(ya, ya)),
                             __fmul_rn(za, za));
        float sb = __fadd_rn(__fadd_rn(__fmul_rn(xb, xb), __fmul_rn(yb, yb)),
                             __fmul_rn(zb, zb));
        Q[k] = make_float4(xa + xa, xb + xb, ya + ya, yb + yb);
        R[k] = make_float4(za + za, zb + zb, sa, sb);
    }
    __syncthreads();

    const int q = tid >> 4;       // query within tile
    const int t = tid & 15;       // lane within query group
    const int m = mtile * QPB + q;

    const size_t pbase = ((size_t)b * N2_ + m) * 3;
    const float x2 = p2[pbase + 0];
    const float y2 = p2[pbase + 1];
    const float z2 = p2[pbase + 2];
    const float s2 = __fadd_rn(__fadd_rn(__fmul_rn(x2, x2), __fmul_rn(y2, y2)),
                               __fmul_rn(z2, z2));

    const vf2 x2v = {x2, x2};
    const vf2 y2v = {y2, y2};
    const vf2 z2v = {z2, z2};
    const vf2 s2v = {s2, s2};

    unsigned k0 = UINT_MAX, k1 = UINT_MAX, k2 = UINT_MAX, k3 = UINT_MAX;

    // 32 pair-iterations: candidates (2k, 2k+1), k = t + 16*j.
#pragma unroll 4
    for (int j = 0; j < N1_ / (2 * TPQ); ++j) {
        const int k = t + TPQ * j;
        float4 qv = Q[k];
        float4 rv = R[k];
        vf2 qx = {qv.x, qv.y};
        vf2 qy = {qv.z, qv.w};
        vf2 rz = {rv.x, rv.y};
        vf2 rs = {rv.z, rv.w};
        // Scan metric: 3 pk_fma (neg mods free) + 1 pk_add.
        vf2 t0 = __builtin_elementwise_fma(-qx, x2v, s2v);
        vf2 t1 = __builtin_elementwise_fma(-qy, y2v, t0);
        vf2 t2 = __builtin_elementwise_fma(-rz, z2v, t1);
        vf2 dd = t2 + rs;
        const unsigned un = (unsigned)(2 * k);
        unsigned ka = (__float_as_uint(fmaxf(dd.x, 0.f)) & 0xFFFFFC00u) | un;
        unsigned kb = (__float_as_uint(fmaxf(dd.y, 0.f)) & 0xFFFFFC00u) | (un + 1u);
        KINS4(ka, k0, k1, k2, k3);
        KINS4(kb, k0, k1, k2, k3);
    }

    // Butterfly-merge the 16 lanes' top-4 keys (u32 order, exact).
    for (int mask = 1; mask < TPQ; mask <<= 1) {
        unsigned p0 = (unsigned)__shfl_xor((int)k0, mask, TPQ);
        unsigned p1_ = (unsigned)__shfl_xor((int)k1, mask, TPQ);
        unsigned p2_ = (unsigned)__shfl_xor((int)k2, mask, TPQ);
        unsigned p3_ = (unsigned)__shfl_xor((int)k3, mask, TPQ);
        KINS4(p0,  k0, k1, k2, k3);
        KINS4(p1_, k0, k1, k2, k3);
        KINS4(p2_, k0, k1, k2, k3);
        KINS4(p3_, k0, k1, k2, k3);
    }

    if (t == 0) {
        int   ix[4];
        float dx[4];
#pragma unroll
        for (int k = 0; k < 4; ++k) {
            const unsigned a = k == 0 ? k0 : k == 1 ? k1 : k == 2 ? k2 : k3;
            const int n  = (int)(a & 1023u);
            const int kk = n >> 1;
            const int h  = n & 1;
            const float cx = h ? Q[kk].y : Q[kk].x;   // 2x
            const float cy = h ? Q[kk].w : Q[kk].z;   // 2y
            const float cz = h ? R[kk].y : R[kk].x;   // 2z
            const float cs = h ? R[kk].w : R[kk].z;   // s1
            // EXACT reference arithmetic: dd = (s2 - dot2) + s1
            dx[k] = __fadd_rn(__fsub_rn(s2,
                __fadd_rn(__fadd_rn(__fmul_rn(x2, cx), __fmul_rn(y2, cy)),
                          __fmul_rn(z2, cz))), cs);
            ix[k] = n;
        }
        // Exact lexicographic (d, idx) sort-4: (0,1)(2,3)(0,2)(1,3)(1,2)
#define CSWAP(a, b) do {                                            \
        bool sw = (dx[b] < dx[a]) || (dx[b] == dx[a] && ix[b] < ix[a]); \
        float td = sw ? dx[b] : dx[a]; dx[b] = sw ? dx[a] : dx[b]; dx[a] = td; \
        int   ti = sw ? ix[b] : ix[a]; ix[b] = sw ? ix[a] : ix[b]; ix[a] = ti; \
    } while (0)
        CSWAP(0, 1); CSWAP(2, 3); CSWAP(0, 2); CSWAP(1, 3); CSWAP(1, 2);
#undef CSWAP

        const float r0 = 1.0f / __fadd_rn(dx[0], 1e-8f);
        const float r1 = 1.0f / __fadd_rn(dx[1], 1e-8f);
        const float r2 = 1.0f / __fadd_rn(dx[2], 1e-8f);
        const float s  = __fadd_rn(__fadd_rn(r0, r1), r2);
        const size_t o = (size_t)b * N2_ + m;
        wsi[o] = make_int4(ix[0], ix[1], ix[2], 0);
        wsw[o] = make_float4(r0 / s, r1 / s, r2 / s, 0.0f);
    }
}

// ---------------------------------------------------------------------------
// Kernel 2 (v4): gather + blend — byte-exact round-6 version (control).
// ---------------------------------------------------------------------------

__global__ __launch_bounds__(256) void blend_kernel(
    const float* __restrict__ x1, const int4* __restrict__ wsi,
    const float4* __restrict__ wsw, float* __restrict__ out) {
    __shared__ float4 L4[N1_];   // 16 KB, XOR-swizzled channel-interleaved

    int bid = blockIdx.x;
    const int mhalf = bid & 1;
    const int ct    = (bid >> 1) & 63;   // 64 channel tiles of 4
    const int b     = bid >> 7;
    const int tid   = threadIdx.x;

    // Prefetch idx/weights for all 8 m-iterations.
    const size_t wbase = (size_t)b * N2_ + (size_t)mhalf * 2048;
    int4   id[8];
    float4 w[8];
#pragma unroll
    for (int mb = 0; mb < 8; ++mb) {
        id[mb] = wsi[wbase + mb * 256 + tid];
        w[mb]  = wsw[wbase + mb * 256 + tid];
    }

    // Stage 4 channels, register-transposed into interleaved LDS.
    const float* src = x1 + ((size_t)b * C_ + (size_t)ct * 4) * N1_;
    float4 v[4];
#pragma unroll
    for (int c = 0; c < 4; ++c)
        v[c] = reinterpret_cast<const float4*>(src + (size_t)c * N1_)[tid];
#pragma unroll
    for (int e = 0; e < 4; ++e) {
        const int n = 4 * tid + e;
        L4[n ^ ((n >> 3) & 7)] = make_float4((&v[0].x)[e], (&v[1].x)[e],
                                             (&v[2].x)[e], (&v[3].x)[e]);
    }
    __syncthreads();

    const size_t obase = ((size_t)b * C_ + (size_t)ct * 4) * N2_;
#pragma unroll
    for (int mb = 0; mb < 8; ++mb) {
        const int m = mhalf * 2048 + mb * 256 + tid;
        const int na = id[mb].x, nb = id[mb].y, nc = id[mb].z;
        const float4 A  = L4[na ^ ((na >> 3) & 7)];
        const float4 Bv = L4[nb ^ ((nb >> 3) & 7)];
        const float4 Cv = L4[nc ^ ((nc >> 3) & 7)];
        const float wx = w[mb].x, wy = w[mb].y, wz = w[mb].z;
#pragma unroll
        for (int r = 0; r < 4; ++r) {
            float acc = __fadd_rn(__fadd_rn(__fmul_rn((&A.x)[r],  wx),
                                            __fmul_rn((&Bv.x)[r], wy)),
                                  __fmul_rn((&Cv.x)[r], wz));
            __builtin_nontemporal_store(acc, &out[obase + (size_t)r * N2_ + m]);
        }
    }
}

extern "C" void kernel_launch(void* const* d_in, const int* in_sizes, int n_in,
                              void* d_out, int out_size, void* d_ws, size_t ws_size,
                              hipStream_t stream) {
    const float* p1 = (const float*)d_in[0];   // [B, N1, 3]
    const float* x1 = (const float*)d_in[1];   // [B, C, N1]
    const float* p2 = (const float*)d_in[2];   // [B, N2, 3]
    float* out = (float*)d_out;                // [B, C, N2]

    int4*   wsi = (int4*)d_ws;
    float4* wsw = (float4*)((char*)d_ws + (size_t)B_ * N2_ * sizeof(int4));

    knn_kernel<<<B_ * (N2_ / QPB), 256, 0, stream>>>(p1, p2, wsi, wsw);
    blend_kernel<<<B_ * (C_ / 4) * 2, 256, 0, stream>>>(x1, wsi, wsw, out);
}

// Round 18
// 26.665 us; speedup vs baseline: 2.6343x; 1.0541x over previous
//
#include <hip/hip_runtime.h>
#include <cfloat>
#include <climits>

#define B_   8
#define N1_  1024
#define N2_  4096
#define C_   256
#define TPQ  8                  // lanes per query
#define QPB  (256 / TPQ)        // 32 queries per block

typedef float vf2 __attribute__((ext_vector_type(2)));

__device__ __forceinline__ unsigned umin_(unsigned a, unsigned b) { return a < b ? a : b; }

// Guaranteed single-op median-of-3 (u32). VOP3, all-VGPR operands.
__device__ __forceinline__ unsigned umed3_(unsigned a, unsigned b, unsigned c) {
    unsigned d;
    asm("v_med3_u32 %0, %1, %2, %3" : "=v"(d) : "v"(a), "v"(b), "v"(c));
    return d;
}

// Sorted-quad insert (invariant k0<=k1<=k2<=k3): min + 3x med3 = 4 VALU ops.
#define KINS4(k, k0, k1, k2, k3) do {                 \
    unsigned _n1 = umed3_((k), k0, k1);               \
    unsigned _n2 = umed3_((k), k1, k2);               \
    unsigned _n3 = umed3_((k), k2, k3);               \
    k0 = umin_((k), k0);  k1 = _n1;  k2 = _n2;  k3 = _n3; \
} while (0)

// ---------------------------------------------------------------------------
// Kernel 1 (v13): 3-NN. R17 algorithm (pair-interleaved packed-FMA scan,
// trunc-key top-4, EXACT rescue — validated R9/R14/R15/R17) with:
//  - TPQ=8: 32 queries/block, 1024 blocks. Merge 4->3 butterfly steps
//    (halves per-eval merge cost); staging amortized over 2x queries.
//    Selection set unchanged: union of 8 lanes' top-4 still contains the
//    true top-4 (any global top-4 element is top-4 within its lane subset).
//  - v_pk_max_f32 clamp: 1 packed op clamps both pair distances.
// per eval: 2 dist + 0.5 clamp + 1 and_or + 4 KINS = 7.5 source ops.
// ---------------------------------------------------------------------------
__global__ __launch_bounds__(256) void knn_kernel(
    const float* __restrict__ p1, const float* __restrict__ p2,
    int4* __restrict__ wsi, float4* __restrict__ wsw) {
#pragma clang fp contract(off)
    __shared__ float4 Q[N1_ / 2];   // 8 KB
    __shared__ float4 R[N1_ / 2];   // 8 KB

    const int tid   = threadIdx.x;
    const int b     = blockIdx.x >> 7;     // 128 query-tiles per batch
    const int mtile = blockIdx.x & 127;

    // Stage coarse points, pair-interleaved, exact pre-doubling (R3 layout).
    for (int k = tid; k < N1_ / 2; k += 256) {
        const float* pa = &p1[((size_t)b * N1_ + 2 * k) * 3];
        float xa = pa[0], ya = pa[1], za = pa[2];
        float xb = pa[3], yb = pa[4], zb = pa[5];
        float sa = __fadd_rn(__fadd_rn(__fmul_rn(xa, xa), __fmul_rn(ya, ya)),
                             __fmul_rn(za, za));
        float sb = __fadd_rn(__fadd_rn(__fmul_rn(xb, xb), __fmul_rn(yb, yb)),
                             __fmul_rn(zb, zb));
        Q[k] = make_float4(xa + xa, xb + xb, ya + ya, yb + yb);
        R[k] = make_float4(za + za, zb + zb, sa, sb);
    }
    __syncthreads();

    const int q = tid >> 3;       // query within tile (0..31)
    const int t = tid & 7;        // lane within query group
    const int m = mtile * QPB + q;

    const size_t pbase = ((size_t)b * N2_ + m) * 3;
    const float x2 = p2[pbase + 0];
    const float y2 = p2[pbase + 1];
    const float z2 = p2[pbase + 2];
    const float s2 = __fadd_rn(__fadd_rn(__fmul_rn(x2, x2), __fmul_rn(y2, y2)),
                               __fmul_rn(z2, z2));

    const vf2 x2v = {x2, x2};
    const vf2 y2v = {y2, y2};
    const vf2 z2v = {z2, z2};
    const vf2 s2v = {s2, s2};
    const vf2 zero = {0.f, 0.f};

    unsigned k0 = UINT_MAX, k1 = UINT_MAX, k2 = UINT_MAX, k3 = UINT_MAX;

    // 64 pair-iterations: candidates (2k, 2k+1), k = t + 8*j.
#pragma unroll 4
    for (int j = 0; j < N1_ / (2 * TPQ); ++j) {
        const int k = t + TPQ * j;
        float4 qv = Q[k];
        float4 rv = R[k];
        vf2 qx = {qv.x, qv.y};
        vf2 qy = {qv.z, qv.w};
        vf2 rz = {rv.x, rv.y};
        vf2 rs = {rv.z, rv.w};
        // Scan metric: 3 pk_fma (neg mods free) + 1 pk_add + 1 pk_max.
        vf2 t0 = __builtin_elementwise_fma(-qx, x2v, s2v);
        vf2 t1 = __builtin_elementwise_fma(-qy, y2v, t0);
        vf2 t2 = __builtin_elementwise_fma(-rz, z2v, t1);
        vf2 dd = t2 + rs;
        vf2 ddc = __builtin_elementwise_max(dd, zero);   // v_pk_max_f32
        const unsigned un = (unsigned)(2 * k);
        unsigned ka = (__float_as_uint(ddc.x) & 0xFFFFFC00u) | un;
        unsigned kb = (__float_as_uint(ddc.y) & 0xFFFFFC00u) | (un + 1u);
        KINS4(ka, k0, k1, k2, k3);
        KINS4(kb, k0, k1, k2, k3);
    }

    // Butterfly-merge the 8 lanes' top-4 keys (u32 order, exact).
    for (int mask = 1; mask < TPQ; mask <<= 1) {
        unsigned p0 = (unsigned)__shfl_xor((int)k0, mask, TPQ);
        unsigned p1_ = (unsigned)__shfl_xor((int)k1, mask, TPQ);
        unsigned p2_ = (unsigned)__shfl_xor((int)k2, mask, TPQ);
        unsigned p3_ = (unsigned)__shfl_xor((int)k3, mask, TPQ);
        KINS4(p0,  k0, k1, k2, k3);
        KINS4(p1_, k0, k1, k2, k3);
        KINS4(p2_, k0, k1, k2, k3);
        KINS4(p3_, k0, k1, k2, k3);
    }

    if (t == 0) {
        int   ix[4];
        float dx[4];
#pragma unroll
        for (int k = 0; k < 4; ++k) {
            const unsigned a = k == 0 ? k0 : k == 1 ? k1 : k == 2 ? k2 : k3;
            const int n  = (int)(a & 1023u);
            const int kk = n >> 1;
            const int h  = n & 1;
            const float cx = h ? Q[kk].y : Q[kk].x;   // 2x
            const float cy = h ? Q[kk].w : Q[kk].z;   // 2y
            const float cz = h ? R[kk].y : R[kk].x;   // 2z
            const float cs = h ? R[kk].w : R[kk].z;   // s1
            // EXACT reference arithmetic: dd = (s2 - dot2) + s1
            dx[k] = __fadd_rn(__fsub_rn(s2,
                __fadd_rn(__fadd_rn(__fmul_rn(x2, cx), __fmul_rn(y2, cy)),
                          __fmul_rn(z2, cz))), cs);
            ix[k] = n;
        }
        // Exact lexicographic (d, idx) sort-4: (0,1)(2,3)(0,2)(1,3)(1,2)
#define CSWAP(a, b) do {                                            \
        bool sw = (dx[b] < dx[a]) || (dx[b] == dx[a] && ix[b] < ix[a]); \
        float td = sw ? dx[b] : dx[a]; dx[b] = sw ? dx[a] : dx[b]; dx[a] = td; \
        int   ti = sw ? ix[b] : ix[a]; ix[b] = sw ? ix[a] : ix[b]; ix[a] = ti; \
    } while (0)
        CSWAP(0, 1); CSWAP(2, 3); CSWAP(0, 2); CSWAP(1, 3); CSWAP(1, 2);
#undef CSWAP

        const float r0 = 1.0f / __fadd_rn(dx[0], 1e-8f);
        const float r1 = 1.0f / __fadd_rn(dx[1], 1e-8f);
        const float r2 = 1.0f / __fadd_rn(dx[2], 1e-8f);
        const float s  = __fadd_rn(__fadd_rn(r0, r1), r2);
        const size_t o = (size_t)b * N2_ + m;
        wsi[o] = make_int4(ix[0], ix[1], ix[2], 0);
        wsw[o] = make_float4(r0 / s, r1 / s, r2 / s, 0.0f);
    }
}

// ---------------------------------------------------------------------------
// Kernel 2 (v4): gather + blend — byte-exact round-6 version (control).
// ---------------------------------------------------------------------------

__global__ __launch_bounds__(256) void blend_kernel(
    const float* __restrict__ x1, const int4* __restrict__ wsi,
    const float4* __restrict__ wsw, float* __restrict__ out) {
    __shared__ float4 L4[N1_];   // 16 KB, XOR-swizzled channel-interleaved

    int bid = blockIdx.x;
    const int mhalf = bid & 1;
    const int ct    = (bid >> 1) & 63;   // 64 channel tiles of 4
    const int b     = bid >> 7;
    const int tid   = threadIdx.x;

    // Prefetch idx/weights for all 8 m-iterations.
    const size_t wbase = (size_t)b * N2_ + (size_t)mhalf * 2048;
    int4   id[8];
    float4 w[8];
#pragma unroll
    for (int mb = 0; mb < 8; ++mb) {
        id[mb] = wsi[wbase + mb * 256 + tid];
        w[mb]  = wsw[wbase + mb * 256 + tid];
    }

    // Stage 4 channels, register-transposed into interleaved LDS.
    const float* src = x1 + ((size_t)b * C_ + (size_t)ct * 4) * N1_;
    float4 v[4];
#pragma unroll
    for (int c = 0; c < 4; ++c)
        v[c] = reinterpret_cast<const float4*>(src + (size_t)c * N1_)[tid];
#pragma unroll
    for (int e = 0; e < 4; ++e) {
        const int n = 4 * tid + e;
        L4[n ^ ((n >> 3) & 7)] = make_float4((&v[0].x)[e], (&v[1].x)[e],
                                             (&v[2].x)[e], (&v[3].x)[e]);
    }
    __syncthreads();

    const size_t obase = ((size_t)b * C_ + (size_t)ct * 4) * N2_;
#pragma unroll
    for (int mb = 0; mb < 8; ++mb) {
        const int m = mhalf * 2048 + mb * 256 + tid;
        const int na = id[mb].x, nb = id[mb].y, nc = id[mb].z;
        const float4 A  = L4[na ^ ((na >> 3) & 7)];
        const float4 Bv = L4[nb ^ ((nb >> 3) & 7)];
        const float4 Cv = L4[nc ^ ((nc >> 3) & 7)];
        const float wx = w[mb].x, wy = w[mb].y, wz = w[mb].z;
#pragma unroll
        for (int r = 0; r < 4; ++r) {
            float acc = __fadd_rn(__fadd_rn(__fmul_rn((&A.x)[r],  wx),
                                            __fmul_rn((&Bv.x)[r], wy)),
                                  __fmul_rn((&Cv.x)[r], wz));
            __builtin_nontemporal_store(acc, &out[obase + (size_t)r * N2_ + m]);
        }
    }
}

extern "C" void kernel_launch(void* const* d_in, const int* in_sizes, int n_in,
                              void* d_out, int out_size, void* d_ws, size_t ws_size,
                              hipStream_t stream) {
    const float* p1 = (const float*)d_in[0];   // [B, N1, 3]
    const float* x1 = (const float*)d_in[1];   // [B, C, N1]
    const float* p2 = (const float*)d_in[2];   // [B, N2, 3]
    float* out = (float*)d_out;                // [B, C, N2]

    int4*   wsi = (int4*)d_ws;
    float4* wsw = (float4*)((char*)d_ws + (size_t)B_ * N2_ * sizeof(int4));

    knn_kernel<<<B_ * (N2_ / QPB), 256, 0, stream>>>(p1, p2, wsi, wsw);
    blend_kernel<<<B_ * (C_ / 4) * 2, 256, 0, stream>>>(x1, wsi, wsw, out);
}